// Round 13
// baseline (208.440 us; speedup 1.0000x reference)
//
#include <hip/hip_runtime.h>
#include <hip/hip_bf16.h>

// FraudDetectionHybrid: h1=tanh(x@W1^T+b1); h2=tanh(h1@W2^T+b2);
// sq_ij=|h2_i|^2+|h2_j|^2-2*h2_i.h2_j; out=exp(-g*sq)@Wc^T+bc
// All-fp8 (e4m3, unit MX scales, data pre-scaled by 2^k), 16x16x128 MFMA,
// zero-conflict 16-row fragment shape (2-region LDS, 64B rows).
// GEMM: R11-verified 128^2 tile, 32KiB single-buffer, 4 blocks/CU.
// Gram: R10 128^2 triangle structure with BK=256 (2 k-steps per stage batch,
//       16 drains instead of 32; 64KiB LDS is free at the 2-blocks/CU
//       grid-capped occupancy). R12's 64x128 tiling reverted (1.5x staging).

#define NROWS 4096
#define HID   4096
#define INDIM 512
#define GAMMA_F 5e-4f

typedef float f32x4  __attribute__((ext_vector_type(4)));
typedef int   i32x4  __attribute__((ext_vector_type(4)));
typedef int   i32x8  __attribute__((ext_vector_type(8)));

#define SCALE1 0x7F7F7F7F   // e8m0 = 127 -> 2^0 in all bytes; opsel-independent

#define MFMA16(d, a, b) \
    d = __builtin_amdgcn_mfma_scale_f32_16x16x128_f8f6f4( \
        a, b, d, 0, 0, 0, SCALE1, 0, SCALE1)

// f32 -> OCP e4m3fn, RNE, saturate to 448, subnormals handled
__device__ __forceinline__ unsigned char f2e4m3(float x) {
  unsigned int u = __float_as_uint(x);
  unsigned char s = (unsigned char)((u >> 24) & 0x80u);
  float a = fabsf(x);
  if (a >= 448.f) return s | 0x7E;
  if (a < 0.015625f) {                      // below 2^-6: subnormal (2^-9 ulp)
    int q = (int)rintf(a * 512.f);
    return s | (unsigned char)q;
  }
  unsigned int ua = u & 0x7fffffffu;
  ua += 0x7FFFFu + ((ua >> 20) & 1u);       // RNE at mantissa bit 20
  int e = (int)(ua >> 23) - 127;
  unsigned int m = (ua >> 20) & 7u;
  return s | (unsigned char)(((e + 7) << 3) | m);
}

// fused: out/norms init + cast x*16, W1*32, W2*128 to fp8 (8-float chunks)
__global__ void prep(const float* __restrict__ x, const float* __restrict__ W1,
                     const float* __restrict__ W2, const float* __restrict__ bc,
                     unsigned char* __restrict__ xq, unsigned char* __restrict__ w1q,
                     unsigned char* __restrict__ w2q,
                     float* __restrict__ out, float* __restrict__ norms) {
  const int gi = blockIdx.x * blockDim.x + threadIdx.x;
  if (gi < NROWS) { out[gi] = bc[0]; norms[gi] = 0.f; }
  const int NX  = NROWS * INDIM / 8;
  const int NW2 = HID * HID / 8;
  const int total = 2 * NX + NW2;
  const int stride = gridDim.x * blockDim.x;
  for (int i = gi; i < total; i += stride) {
    const float* src; unsigned char* dst; float sc; int j;
    if (i < NX)          { src = x;  dst = xq;  sc = 16.f;  j = i; }
    else if (i < 2 * NX) { src = W1; dst = w1q; sc = 32.f;  j = i - NX; }
    else                 { src = W2; dst = w2q; sc = 128.f; j = i - 2 * NX; }
    float4 v0 = ((const float4*)src)[j * 2];
    float4 v1 = ((const float4*)src)[j * 2 + 1];
    unsigned int r0 = (unsigned int)f2e4m3(v0.x * sc)
                    | ((unsigned int)f2e4m3(v0.y * sc) << 8)
                    | ((unsigned int)f2e4m3(v0.z * sc) << 16)
                    | ((unsigned int)f2e4m3(v0.w * sc) << 24);
    unsigned int r1 = (unsigned int)f2e4m3(v1.x * sc)
                    | ((unsigned int)f2e4m3(v1.y * sc) << 8)
                    | ((unsigned int)f2e4m3(v1.z * sc) << 16)
                    | ((unsigned int)f2e4m3(v1.w * sc) << 24);
    uint2 o; o.x = r0; o.y = r1;
    ((uint2*)dst)[j] = o;
  }
}

__device__ __forceinline__ void gload16(const void* g, void* l) {
  __builtin_amdgcn_global_load_lds(
      (const __attribute__((address_space(1))) void*)g,
      (__attribute__((address_space(3))) void*)l, 16, 0, 0);
}

// one i32x8 operand = two b128 from the two LDS regions
#define LDFRAG(dst, base0, off, RSTRIDE) do {                       \
    i32x4 lo_ = *(const i32x4*)((base0) + (off));                   \
    i32x4 hi_ = *(const i32x4*)((base0) + (RSTRIDE) + (off));       \
    dst = __builtin_shufflevector(lo_, hi_, 0, 1, 2, 3, 4, 5, 6, 7); } while (0)

// ---------------------------------------------------------------------------
// fp8 NT GEMM (R11-verified, 92.6us): BM=BN=128, BK=128 B, 4 waves (2x2),
// wave tile 64x64 = 4mi x 4nj of 16x16, K=128/MFMA. 32 KiB single-buffer ->
// 4 blocks/CU: cross-block TLP hides the vmcnt(0)+barrier drains.
// EPI 0: Hout = e4m3(8*tanh(acc/512 + bias));
// EPI 2: Hout = e4m3(8*tanh(acc/1024 + bias)) + row-norm atomics (f32 v).
// ---------------------------------------------------------------------------
template <int EPI>
__global__ __launch_bounds__(256, 4)
void gemm128_fp8(const unsigned char* __restrict__ A, const unsigned char* __restrict__ B,
                 int K, int N,
                 const float* __restrict__ bias, unsigned char* __restrict__ Hout,
                 float* __restrict__ norms_out) {
  __shared__ __align__(16) unsigned char As[2][128 * 64];
  __shared__ __align__(16) unsigned char Bs[2][128 * 64];

  const int tid  = threadIdx.x;
  const int lane = tid & 63;
  const int wave = tid >> 6;
  const int wr = wave >> 1, wc = wave & 1;   // 2x2 wave grid, 64x64 out each
  const int fr = lane & 15, fq = lane >> 4;

  const int nwg = gridDim.x;                  // 1024, %8==0
  const int cpx = nwg >> 3;
  const int bid = blockIdx.x;
  const int swzb = (bid & 7) * cpx + (bid >> 3);
  const int nbx = N >> 7;
  const int brow = (swzb / nbx) << 7;
  const int bcol = (swzb % nbx) << 7;

  const unsigned char* ap[4]; const unsigned char* bp[4]; int ldq[4];
#pragma unroll
  for (int q = 0; q < 4; ++q) {
    int idx = q * 256 + tid;
    int h   = idx >> 9;
    int row = (idx >> 2) & 127;
    int c   = idx & 3;
    int gcol = ((((c ^ ((row >> 1) & 3)) << 1) | h) << 4);
    ap[q] = A + (size_t)(brow + row) * K + gcol;
    bp[q] = B + (size_t)(bcol + row) * K + gcol;
    ldq[q] = (q * 256 + wave * 64) * 16;
  }

  int aoff[4], boff[4];
#pragma unroll
  for (int mi = 0; mi < 4; ++mi) {
    int row = wr * 64 + mi * 16 + fr;
    aoff[mi] = row * 64 + ((fq ^ ((row >> 1) & 3)) << 4);
  }
#pragma unroll
  for (int nj = 0; nj < 4; ++nj) {
    int row = wc * 64 + nj * 16 + fr;
    boff[nj] = row * 64 + ((fq ^ ((row >> 1) & 3)) << 4);
  }

  f32x4 acc[4][4] = {};

  for (int t = 0; t < (K >> 7); ++t) {
    __syncthreads();                 // WAR: previous tile's reads done
    {
      int kk = t * 128;
      gload16(ap[0] + kk, &As[0][0] + ldq[0]);
      gload16(ap[1] + kk, &As[0][0] + ldq[1]);
      gload16(ap[2] + kk, &As[0][0] + ldq[2]);
      gload16(ap[3] + kk, &As[0][0] + ldq[3]);
      gload16(bp[0] + kk, &Bs[0][0] + ldq[0]);
      gload16(bp[1] + kk, &Bs[0][0] + ldq[1]);
      gload16(bp[2] + kk, &Bs[0][0] + ldq[2]);
      gload16(bp[3] + kk, &Bs[0][0] + ldq[3]);
    }
    __syncthreads();                 // implicit vmcnt(0): staging landed

    i32x8 af[4], bf[4];
#pragma unroll
    for (int mi = 0; mi < 4; ++mi) LDFRAG(af[mi], &As[0][0], aoff[mi], 8192);
#pragma unroll
    for (int nj = 0; nj < 4; ++nj) LDFRAG(bf[nj], &Bs[0][0], boff[nj], 8192);
#pragma unroll
    for (int mi = 0; mi < 4; ++mi)
#pragma unroll
      for (int nj = 0; nj < 4; ++nj) MFMA16(acc[mi][nj], af[mi], bf[nj]);
  }

  // C/D layout (16x16): col = lane&15, row = (lane>>4)*4 + reg
  const float rescale = (EPI == 0) ? (1.f / 512.f) : (1.f / 1024.f);
  float bv[4];
#pragma unroll
  for (int nj = 0; nj < 4; ++nj) bv[nj] = bias[bcol + wc * 64 + nj * 16 + fr];
#pragma unroll
  for (int mi = 0; mi < 4; ++mi) {
    int row0 = brow + wr * 64 + mi * 16 + fq * 4;
#pragma unroll
    for (int rr = 0; rr < 4; ++rr) {
      float ns = 0.f;
#pragma unroll
      for (int nj = 0; nj < 4; ++nj) {
        int col = bcol + wc * 64 + nj * 16 + fr;
        float v = tanhf(acc[mi][nj][rr] * rescale + bv[nj]);
        Hout[(size_t)(row0 + rr) * N + col] = f2e4m3(8.f * v);
        if (EPI == 2) ns += v * v;
      }
      if (EPI == 2) {
        ns += __shfl_xor(ns, 1);
        ns += __shfl_xor(ns, 2);
        ns += __shfl_xor(ns, 4);
        ns += __shfl_xor(ns, 8);
        if (fr == 0) atomicAdd(&norms_out[row0 + rr], ns);
      }
    }
  }
}

// ---------------------------------------------------------------------------
// Triangular gram, fp8, BK=256: 128x128 tiles over the lower triangle
// (528 blocks, grid-capped ~2 blocks/CU), 4 waves (2x2). LDS
// [kstep][region][128][64B] x2 = 64 KiB single-buffer (free at 2 blocks/CU).
// 16 stage batches (vs 32 at BK=128) -> half the vmcnt(0)+barrier drains.
// kstep 1 = global byte +128, LDS +16384; geometry otherwise identical to
// the R10-verified BK=128 layout. sq = n_r + n_c - acc/32.
// ---------------------------------------------------------------------------
__global__ __launch_bounds__(256, 2)
void gram_tri(const unsigned char* __restrict__ H, int K,
              const float* __restrict__ norms, const float* __restrict__ Wc,
              float* __restrict__ out) {
  __shared__ __align__(16) unsigned char As[2][2][128 * 64];   // 32 KiB
  __shared__ __align__(16) unsigned char Bs[2][2][128 * 64];   // 32 KiB

  const int tid  = threadIdx.x;
  const int lane = tid & 63;
  const int wave = tid >> 6;
  const int wr = wave >> 1, wc = wave & 1;
  const int fr = lane & 15, fq = lane >> 4;

  const int bid = blockIdx.x;
  const int swzb = (bid & 7) * 66 + (bid >> 3);
  int I = (int)((sqrtf(8.0f * (float)swzb + 1.0f) - 1.0f) * 0.5f);
  while ((I + 1) * (I + 2) / 2 <= swzb) ++I;
  while (I * (I + 1) / 2 > swzb) --I;
  const int J = swzb - I * (I + 1) / 2;
  const int brow = I << 7, bcol = J << 7;
  const bool diag = (I == J);

  // staging map (kstep 0; kstep 1 = ap[q]+128 global, +16384 LDS)
  const unsigned char* ap[4]; const unsigned char* bp[4]; int ldq[4];
#pragma unroll
  for (int q = 0; q < 4; ++q) {
    int idx = q * 256 + tid;
    int h   = idx >> 9;
    int row = (idx >> 2) & 127;
    int c   = idx & 3;
    int gcol = ((((c ^ ((row >> 1) & 3)) << 1) | h) << 4);
    ap[q] = H + (size_t)(brow + row) * K + gcol;
    bp[q] = H + (size_t)(bcol + row) * K + gcol;
    ldq[q] = (q * 256 + wave * 64) * 16;
  }

  int aoff[4], boff[4];
#pragma unroll
  for (int mi = 0; mi < 4; ++mi) {
    int row = wr * 64 + mi * 16 + fr;
    aoff[mi] = row * 64 + ((fq ^ ((row >> 1) & 3)) << 4);
  }
#pragma unroll
  for (int nj = 0; nj < 4; ++nj) {
    int row = wc * 64 + nj * 16 + fr;
    boff[nj] = row * 64 + ((fq ^ ((row >> 1) & 3)) << 4);
  }

  f32x4 acc[4][4] = {};

  for (int t = 0; t < (K >> 8); ++t) {          // 16 stage batches
    __syncthreads();                 // WAR: previous batch's reads done
    {
      int kk = t * 256;
      // kstep 0
      gload16(ap[0] + kk, &As[0][0][0] + ldq[0]);
      gload16(ap[1] + kk, &As[0][0][0] + ldq[1]);
      gload16(ap[2] + kk, &As[0][0][0] + ldq[2]);
      gload16(ap[3] + kk, &As[0][0][0] + ldq[3]);
      gload16(bp[0] + kk, &Bs[0][0][0] + ldq[0]);
      gload16(bp[1] + kk, &Bs[0][0][0] + ldq[1]);
      gload16(bp[2] + kk, &Bs[0][0][0] + ldq[2]);
      gload16(bp[3] + kk, &Bs[0][0][0] + ldq[3]);
      // kstep 1
      gload16(ap[0] + kk + 128, &As[1][0][0] + ldq[0]);
      gload16(ap[1] + kk + 128, &As[1][0][0] + ldq[1]);
      gload16(ap[2] + kk + 128, &As[1][0][0] + ldq[2]);
      gload16(ap[3] + kk + 128, &As[1][0][0] + ldq[3]);
      gload16(bp[0] + kk + 128, &Bs[1][0][0] + ldq[0]);
      gload16(bp[1] + kk + 128, &Bs[1][0][0] + ldq[1]);
      gload16(bp[2] + kk + 128, &Bs[1][0][0] + ldq[2]);
      gload16(bp[3] + kk + 128, &Bs[1][0][0] + ldq[3]);
    }
    __syncthreads();                 // implicit vmcnt(0): both k-steps landed

#pragma unroll
    for (int s = 0; s < 2; ++s) {
      i32x8 af[4], bf[4];
#pragma unroll
      for (int mi = 0; mi < 4; ++mi) LDFRAG(af[mi], &As[s][0][0], aoff[mi], 8192);
#pragma unroll
      for (int nj = 0; nj < 4; ++nj) LDFRAG(bf[nj], &Bs[s][0][0], boff[nj], 8192);
#pragma unroll
      for (int mi = 0; mi < 4; ++mi)
#pragma unroll
        for (int nj = 0; nj < 4; ++nj) MFMA16(acc[mi][nj], af[mi], bf[nj]);
    }
  }

  // epilogue: sq = n_r + n_c - acc/32 ; dual-direction reduction (R10-verified)
  float ncol[4], wcv[4];
#pragma unroll
  for (int nj = 0; nj < 4; ++nj) {
    int col = bcol + wc * 64 + nj * 16 + fr;
    ncol[nj] = norms[col];
    wcv[nj]  = Wc[col];
  }
  float colpart[4] = {0.f, 0.f, 0.f, 0.f};
#pragma unroll
  for (int mi = 0; mi < 4; ++mi) {
    int row0 = brow + wr * 64 + mi * 16 + fq * 4;
    float4 nr4  = *(const float4*)&norms[row0];
    float4 wcr4 = *(const float4*)&Wc[row0];
#pragma unroll
    for (int rr = 0; rr < 4; ++rr) {
      float nrow = (rr == 0) ? nr4.x : (rr == 1) ? nr4.y : (rr == 2) ? nr4.z : nr4.w;
      float wrow = (rr == 0) ? wcr4.x : (rr == 1) ? wcr4.y : (rr == 2) ? wcr4.z : wcr4.w;
      float rowpart = 0.f;
#pragma unroll
      for (int nj = 0; nj < 4; ++nj) {
        float sq = nrow + ncol[nj] - acc[mi][nj][rr] * 0.03125f;
        float e = __expf(-GAMMA_F * sq);
        rowpart += e * wcv[nj];
        colpart[nj] += e * wrow;
      }
      rowpart += __shfl_xor(rowpart, 1);
      rowpart += __shfl_xor(rowpart, 2);
      rowpart += __shfl_xor(rowpart, 4);
      rowpart += __shfl_xor(rowpart, 8);
      if (fr == 0) atomicAdd(&out[row0 + rr], rowpart);
    }
  }
  if (!diag) {
#pragma unroll
    for (int nj = 0; nj < 4; ++nj) {
      colpart[nj] += __shfl_xor(colpart[nj], 16);
      colpart[nj] += __shfl_xor(colpart[nj], 32);
      if (fq == 0) atomicAdd(&out[bcol + wc * 64 + nj * 16 + fr], colpart[nj]);
    }
  }
}

extern "C" void kernel_launch(void* const* d_in, const int* in_sizes, int n_in,
                              void* d_out, int out_size, void* d_ws, size_t ws_size,
                              hipStream_t stream) {
  const float* x  = (const float*)d_in[0];  // [4096,512]
  const float* W1 = (const float*)d_in[1];  // [4096,512]
  const float* b1 = (const float*)d_in[2];  // [4096]
  const float* W2 = (const float*)d_in[3];  // [4096,4096]
  const float* b2 = (const float*)d_in[4];  // [4096]
  const float* Wc = (const float*)d_in[5];  // [1,4096]
  const float* bc = (const float*)d_in[6];  // [1]
  float* out = (float*)d_out;               // [4096,1]

  char* ws = (char*)d_ws;
  unsigned char* xq  = (unsigned char*)ws; ws += (size_t)NROWS * INDIM;   // x*16   fp8
  unsigned char* w1q = (unsigned char*)ws; ws += (size_t)HID * INDIM;     // W1*32  fp8
  unsigned char* w2q = (unsigned char*)ws; ws += (size_t)HID * HID;       // W2*128 fp8
  unsigned char* h1q = (unsigned char*)ws; ws += (size_t)NROWS * HID;     // h1*8   fp8
  unsigned char* h2q = (unsigned char*)ws; ws += (size_t)NROWS * HID;     // h2*8   fp8
  float* norms = (float*)ws;                ws += (size_t)NROWS * 4;

  // fused init + casts
  prep<<<2048, 256, 0, stream>>>(x, W1, W2, bc, xq, w1q, w2q, out, norms);

  const int grid = (NROWS / 128) * (HID / 128);  // 1024

  // h1 = tanh((x16 @ W1_32^T)/512 + b1) -> fp8(8*h1)
  gemm128_fp8<0><<<grid, 256, 0, stream>>>(xq, w1q, INDIM, HID, b1, h1q, nullptr);
  // h2 = tanh((h1_8 @ W2_128^T)/1024 + b2) -> fp8(8*h2), norms (f32) fused
  gemm128_fp8<2><<<grid, 256, 0, stream>>>(h1q, w2q, HID, HID, b2, h2q, norms);
  // triangular gram + classifier (fp8, BK=256, 16 drains)
  gram_tri<<<528, 256, 0, stream>>>(h2q, HID, norms, Wc, out);
}

// Round 14
// 190.221 us; speedup vs baseline: 1.0958x; 1.0958x over previous
//
#include <hip/hip_runtime.h>
#include <hip/hip_bf16.h>

// FraudDetectionHybrid: h1=tanh(x@W1^T+b1); h2=tanh(h1@W2^T+b2);
// sq_ij=|h2_i|^2+|h2_j|^2-2*h2_i.h2_j; out=exp(-g*sq)@Wc^T+bc
// All-fp8 (e4m3, unit MX scales, data pre-scaled by 2^k), 16x16x128 MFMA,
// zero-conflict 16-row fragment shape (2-region LDS, 64B rows).
// BANKED COMBO (best measured per kernel, never before run together):
//   GEMM1/2: gemm128 (R11/R13: GEMM2 91.7us; 32KiB, 4 blocks/CU)
//   Gram:    R7/R10 single-buffer 128^2 triangle (72.6us; robust local
//            optimum vs dbuf/T14/64x128/BK=256 — all 4 regressed)
//   prep:    fused init + 3 casts (R8)

#define NROWS 4096
#define HID   4096
#define INDIM 512
#define GAMMA_F 5e-4f

typedef float f32x4  __attribute__((ext_vector_type(4)));
typedef int   i32x4  __attribute__((ext_vector_type(4)));
typedef int   i32x8  __attribute__((ext_vector_type(8)));

#define SCALE1 0x7F7F7F7F   // e8m0 = 127 -> 2^0 in all bytes; opsel-independent

#define MFMA16(d, a, b) \
    d = __builtin_amdgcn_mfma_scale_f32_16x16x128_f8f6f4( \
        a, b, d, 0, 0, 0, SCALE1, 0, SCALE1)

// f32 -> OCP e4m3fn, RNE, saturate to 448, subnormals handled
__device__ __forceinline__ unsigned char f2e4m3(float x) {
  unsigned int u = __float_as_uint(x);
  unsigned char s = (unsigned char)((u >> 24) & 0x80u);
  float a = fabsf(x);
  if (a >= 448.f) return s | 0x7E;
  if (a < 0.015625f) {                      // below 2^-6: subnormal (2^-9 ulp)
    int q = (int)rintf(a * 512.f);
    return s | (unsigned char)q;
  }
  unsigned int ua = u & 0x7fffffffu;
  ua += 0x7FFFFu + ((ua >> 20) & 1u);       // RNE at mantissa bit 20
  int e = (int)(ua >> 23) - 127;
  unsigned int m = (ua >> 20) & 7u;
  return s | (unsigned char)(((e + 7) << 3) | m);
}

// fused: out/norms init + cast x*16, W1*32, W2*128 to fp8 (8-float chunks)
__global__ void prep(const float* __restrict__ x, const float* __restrict__ W1,
                     const float* __restrict__ W2, const float* __restrict__ bc,
                     unsigned char* __restrict__ xq, unsigned char* __restrict__ w1q,
                     unsigned char* __restrict__ w2q,
                     float* __restrict__ out, float* __restrict__ norms) {
  const int gi = blockIdx.x * blockDim.x + threadIdx.x;
  if (gi < NROWS) { out[gi] = bc[0]; norms[gi] = 0.f; }
  const int NX  = NROWS * INDIM / 8;
  const int NW2 = HID * HID / 8;
  const int total = 2 * NX + NW2;
  const int stride = gridDim.x * blockDim.x;
  for (int i = gi; i < total; i += stride) {
    const float* src; unsigned char* dst; float sc; int j;
    if (i < NX)          { src = x;  dst = xq;  sc = 16.f;  j = i; }
    else if (i < 2 * NX) { src = W1; dst = w1q; sc = 32.f;  j = i - NX; }
    else                 { src = W2; dst = w2q; sc = 128.f; j = i - 2 * NX; }
    float4 v0 = ((const float4*)src)[j * 2];
    float4 v1 = ((const float4*)src)[j * 2 + 1];
    unsigned int r0 = (unsigned int)f2e4m3(v0.x * sc)
                    | ((unsigned int)f2e4m3(v0.y * sc) << 8)
                    | ((unsigned int)f2e4m3(v0.z * sc) << 16)
                    | ((unsigned int)f2e4m3(v0.w * sc) << 24);
    unsigned int r1 = (unsigned int)f2e4m3(v1.x * sc)
                    | ((unsigned int)f2e4m3(v1.y * sc) << 8)
                    | ((unsigned int)f2e4m3(v1.z * sc) << 16)
                    | ((unsigned int)f2e4m3(v1.w * sc) << 24);
    uint2 o; o.x = r0; o.y = r1;
    ((uint2*)dst)[j] = o;
  }
}

__device__ __forceinline__ void gload16(const void* g, void* l) {
  __builtin_amdgcn_global_load_lds(
      (const __attribute__((address_space(1))) void*)g,
      (__attribute__((address_space(3))) void*)l, 16, 0, 0);
}

// one i32x8 operand = two b128 from the two LDS regions
#define LDFRAG(dst, base0, off, RSTRIDE) do {                       \
    i32x4 lo_ = *(const i32x4*)((base0) + (off));                   \
    i32x4 hi_ = *(const i32x4*)((base0) + (RSTRIDE) + (off));       \
    dst = __builtin_shufflevector(lo_, hi_, 0, 1, 2, 3, 4, 5, 6, 7); } while (0)

// ---------------------------------------------------------------------------
// fp8 NT GEMM (R11/R13-verified, 91.7us): BM=BN=128, BK=128 B, 4 waves (2x2),
// wave tile 64x64 = 4mi x 4nj of 16x16, K=128/MFMA. 32 KiB single-buffer ->
// 4 blocks/CU: cross-block TLP hides the vmcnt(0)+barrier drains.
// EPI 0: Hout = e4m3(8*tanh(acc/512 + bias));
// EPI 2: Hout = e4m3(8*tanh(acc/1024 + bias)) + row-norm atomics (f32 v).
// ---------------------------------------------------------------------------
template <int EPI>
__global__ __launch_bounds__(256, 4)
void gemm128_fp8(const unsigned char* __restrict__ A, const unsigned char* __restrict__ B,
                 int K, int N,
                 const float* __restrict__ bias, unsigned char* __restrict__ Hout,
                 float* __restrict__ norms_out) {
  __shared__ __align__(16) unsigned char As[2][128 * 64];
  __shared__ __align__(16) unsigned char Bs[2][128 * 64];

  const int tid  = threadIdx.x;
  const int lane = tid & 63;
  const int wave = tid >> 6;
  const int wr = wave >> 1, wc = wave & 1;   // 2x2 wave grid, 64x64 out each
  const int fr = lane & 15, fq = lane >> 4;

  const int nwg = gridDim.x;                  // 1024, %8==0
  const int cpx = nwg >> 3;
  const int bid = blockIdx.x;
  const int swzb = (bid & 7) * cpx + (bid >> 3);
  const int nbx = N >> 7;
  const int brow = (swzb / nbx) << 7;
  const int bcol = (swzb % nbx) << 7;

  const unsigned char* ap[4]; const unsigned char* bp[4]; int ldq[4];
#pragma unroll
  for (int q = 0; q < 4; ++q) {
    int idx = q * 256 + tid;
    int h   = idx >> 9;
    int row = (idx >> 2) & 127;
    int c   = idx & 3;
    int gcol = ((((c ^ ((row >> 1) & 3)) << 1) | h) << 4);
    ap[q] = A + (size_t)(brow + row) * K + gcol;
    bp[q] = B + (size_t)(bcol + row) * K + gcol;
    ldq[q] = (q * 256 + wave * 64) * 16;
  }

  int aoff[4], boff[4];
#pragma unroll
  for (int mi = 0; mi < 4; ++mi) {
    int row = wr * 64 + mi * 16 + fr;
    aoff[mi] = row * 64 + ((fq ^ ((row >> 1) & 3)) << 4);
  }
#pragma unroll
  for (int nj = 0; nj < 4; ++nj) {
    int row = wc * 64 + nj * 16 + fr;
    boff[nj] = row * 64 + ((fq ^ ((row >> 1) & 3)) << 4);
  }

  f32x4 acc[4][4] = {};

  for (int t = 0; t < (K >> 7); ++t) {
    __syncthreads();                 // WAR: previous tile's reads done
    {
      int kk = t * 128;
      gload16(ap[0] + kk, &As[0][0] + ldq[0]);
      gload16(ap[1] + kk, &As[0][0] + ldq[1]);
      gload16(ap[2] + kk, &As[0][0] + ldq[2]);
      gload16(ap[3] + kk, &As[0][0] + ldq[3]);
      gload16(bp[0] + kk, &Bs[0][0] + ldq[0]);
      gload16(bp[1] + kk, &Bs[0][0] + ldq[1]);
      gload16(bp[2] + kk, &Bs[0][0] + ldq[2]);
      gload16(bp[3] + kk, &Bs[0][0] + ldq[3]);
    }
    __syncthreads();                 // implicit vmcnt(0): staging landed

    i32x8 af[4], bf[4];
#pragma unroll
    for (int mi = 0; mi < 4; ++mi) LDFRAG(af[mi], &As[0][0], aoff[mi], 8192);
#pragma unroll
    for (int nj = 0; nj < 4; ++nj) LDFRAG(bf[nj], &Bs[0][0], boff[nj], 8192);
#pragma unroll
    for (int mi = 0; mi < 4; ++mi)
#pragma unroll
      for (int nj = 0; nj < 4; ++nj) MFMA16(acc[mi][nj], af[mi], bf[nj]);
  }

  // C/D layout (16x16): col = lane&15, row = (lane>>4)*4 + reg
  const float rescale = (EPI == 0) ? (1.f / 512.f) : (1.f / 1024.f);
  float bv[4];
#pragma unroll
  for (int nj = 0; nj < 4; ++nj) bv[nj] = bias[bcol + wc * 64 + nj * 16 + fr];
#pragma unroll
  for (int mi = 0; mi < 4; ++mi) {
    int row0 = brow + wr * 64 + mi * 16 + fq * 4;
#pragma unroll
    for (int rr = 0; rr < 4; ++rr) {
      float ns = 0.f;
#pragma unroll
      for (int nj = 0; nj < 4; ++nj) {
        int col = bcol + wc * 64 + nj * 16 + fr;
        float v = tanhf(acc[mi][nj][rr] * rescale + bv[nj]);
        Hout[(size_t)(row0 + rr) * N + col] = f2e4m3(8.f * v);
        if (EPI == 2) ns += v * v;
      }
      if (EPI == 2) {
        ns += __shfl_xor(ns, 1);
        ns += __shfl_xor(ns, 2);
        ns += __shfl_xor(ns, 4);
        ns += __shfl_xor(ns, 8);
        if (fr == 0) atomicAdd(&norms_out[row0 + rr], ns);
      }
    }
  }
}

// ---------------------------------------------------------------------------
// Triangular gram, fp8 (R7/R10-verified, 72.6us): 128x128 tiles over the
// lower triangle (528 blocks), 4 waves (2x2), single-buffer 2-barrier loop,
// 32 KiB LDS (multi-block/CU TLP hides the drains). sq = n_r + n_c - acc/32.
// ---------------------------------------------------------------------------
__global__ __launch_bounds__(256, 2)
void gram_tri(const unsigned char* __restrict__ H, int K,
              const float* __restrict__ norms, const float* __restrict__ Wc,
              float* __restrict__ out) {
  __shared__ __align__(16) unsigned char As[2][128 * 64];
  __shared__ __align__(16) unsigned char Bs[2][128 * 64];

  const int tid  = threadIdx.x;
  const int lane = tid & 63;
  const int wave = tid >> 6;
  const int wr = wave >> 1, wc = wave & 1;
  const int fr = lane & 15, fq = lane >> 4;

  const int bid = blockIdx.x;
  const int swzb = (bid & 7) * 66 + (bid >> 3);
  int I = (int)((sqrtf(8.0f * (float)swzb + 1.0f) - 1.0f) * 0.5f);
  while ((I + 1) * (I + 2) / 2 <= swzb) ++I;
  while (I * (I + 1) / 2 > swzb) --I;
  const int J = swzb - I * (I + 1) / 2;
  const int brow = I << 7, bcol = J << 7;
  const bool diag = (I == J);

  const unsigned char* ap[4]; const unsigned char* bp[4]; int ldq[4];
#pragma unroll
  for (int q = 0; q < 4; ++q) {
    int idx = q * 256 + tid;
    int h   = idx >> 9;
    int row = (idx >> 2) & 127;
    int c   = idx & 3;
    int gcol = ((((c ^ ((row >> 1) & 3)) << 1) | h) << 4);
    ap[q] = H + (size_t)(brow + row) * K + gcol;
    bp[q] = H + (size_t)(bcol + row) * K + gcol;
    ldq[q] = (q * 256 + wave * 64) * 16;
  }

  int aoff[4], boff[4];
#pragma unroll
  for (int mi = 0; mi < 4; ++mi) {
    int row = wr * 64 + mi * 16 + fr;
    aoff[mi] = row * 64 + ((fq ^ ((row >> 1) & 3)) << 4);
  }
#pragma unroll
  for (int nj = 0; nj < 4; ++nj) {
    int row = wc * 64 + nj * 16 + fr;
    boff[nj] = row * 64 + ((fq ^ ((row >> 1) & 3)) << 4);
  }

  f32x4 acc[4][4] = {};

  for (int t = 0; t < (K >> 7); ++t) {
    __syncthreads();
    {
      int kk = t * 128;
      gload16(ap[0] + kk, &As[0][0] + ldq[0]);
      gload16(ap[1] + kk, &As[0][0] + ldq[1]);
      gload16(ap[2] + kk, &As[0][0] + ldq[2]);
      gload16(ap[3] + kk, &As[0][0] + ldq[3]);
      gload16(bp[0] + kk, &Bs[0][0] + ldq[0]);
      gload16(bp[1] + kk, &Bs[0][0] + ldq[1]);
      gload16(bp[2] + kk, &Bs[0][0] + ldq[2]);
      gload16(bp[3] + kk, &Bs[0][0] + ldq[3]);
    }
    __syncthreads();   // implicit vmcnt(0) drain: staging landed

    i32x8 af[4], bf[4];
#pragma unroll
    for (int mi = 0; mi < 4; ++mi) LDFRAG(af[mi], &As[0][0], aoff[mi], 8192);
#pragma unroll
    for (int nj = 0; nj < 4; ++nj) LDFRAG(bf[nj], &Bs[0][0], boff[nj], 8192);
#pragma unroll
    for (int mi = 0; mi < 4; ++mi)
#pragma unroll
      for (int nj = 0; nj < 4; ++nj)
        acc[mi][nj] = __builtin_amdgcn_mfma_scale_f32_16x16x128_f8f6f4(
            af[mi], bf[nj], acc[mi][nj], 0, 0, 0, SCALE1, 0, SCALE1);
  }

  // epilogue: sq = n_r + n_c - acc/32 ; dual-direction reduction
  float ncol[4], wcv[4];
#pragma unroll
  for (int nj = 0; nj < 4; ++nj) {
    int col = bcol + wc * 64 + nj * 16 + fr;
    ncol[nj] = norms[col];
    wcv[nj]  = Wc[col];
  }
  float colpart[4] = {0.f, 0.f, 0.f, 0.f};
#pragma unroll
  for (int mi = 0; mi < 4; ++mi) {
    int row0 = brow + wr * 64 + mi * 16 + fq * 4;
    float4 nr4  = *(const float4*)&norms[row0];
    float4 wcr4 = *(const float4*)&Wc[row0];
#pragma unroll
    for (int rr = 0; rr < 4; ++rr) {
      float nrow = (rr == 0) ? nr4.x : (rr == 1) ? nr4.y : (rr == 2) ? nr4.z : nr4.w;
      float wrow = (rr == 0) ? wcr4.x : (rr == 1) ? wcr4.y : (rr == 2) ? wcr4.z : wcr4.w;
      float rowpart = 0.f;
#pragma unroll
      for (int nj = 0; nj < 4; ++nj) {
        float sq = nrow + ncol[nj] - acc[mi][nj][rr] * 0.03125f;
        float e = __expf(-GAMMA_F * sq);
        rowpart += e * wcv[nj];
        colpart[nj] += e * wrow;
      }
      rowpart += __shfl_xor(rowpart, 1);
      rowpart += __shfl_xor(rowpart, 2);
      rowpart += __shfl_xor(rowpart, 4);
      rowpart += __shfl_xor(rowpart, 8);
      if (fr == 0) atomicAdd(&out[row0 + rr], rowpart);
    }
  }
  if (!diag) {
#pragma unroll
    for (int nj = 0; nj < 4; ++nj) {
      colpart[nj] += __shfl_xor(colpart[nj], 16);
      colpart[nj] += __shfl_xor(colpart[nj], 32);
      if (fq == 0) atomicAdd(&out[bcol + wc * 64 + nj * 16 + fr], colpart[nj]);
    }
  }
}

extern "C" void kernel_launch(void* const* d_in, const int* in_sizes, int n_in,
                              void* d_out, int out_size, void* d_ws, size_t ws_size,
                              hipStream_t stream) {
  const float* x  = (const float*)d_in[0];  // [4096,512]
  const float* W1 = (const float*)d_in[1];  // [4096,512]
  const float* b1 = (const float*)d_in[2];  // [4096]
  const float* W2 = (const float*)d_in[3];  // [4096,4096]
  const float* b2 = (const float*)d_in[4];  // [4096]
  const float* Wc = (const float*)d_in[5];  // [1,4096]
  const float* bc = (const float*)d_in[6];  // [1]
  float* out = (float*)d_out;               // [4096,1]

  char* ws = (char*)d_ws;
  unsigned char* xq  = (unsigned char*)ws; ws += (size_t)NROWS * INDIM;   // x*16   fp8
  unsigned char* w1q = (unsigned char*)ws; ws += (size_t)HID * INDIM;     // W1*32  fp8
  unsigned char* w2q = (unsigned char*)ws; ws += (size_t)HID * HID;       // W2*128 fp8
  unsigned char* h1q = (unsigned char*)ws; ws += (size_t)NROWS * HID;     // h1*8   fp8
  unsigned char* h2q = (unsigned char*)ws; ws += (size_t)NROWS * HID;     // h2*8   fp8
  float* norms = (float*)ws;                ws += (size_t)NROWS * 4;

  // fused init + casts
  prep<<<2048, 256, 0, stream>>>(x, W1, W2, bc, xq, w1q, w2q, out, norms);

  const int grid = (NROWS / 128) * (HID / 128);  // 1024

  // h1 = tanh((x16 @ W1_32^T)/512 + b1) -> fp8(8*h1)
  gemm128_fp8<0><<<grid, 256, 0, stream>>>(xq, w1q, INDIM, HID, b1, h1q, nullptr);
  // h2 = tanh((h1_8 @ W2_128^T)/1024 + b2) -> fp8(8*h2), norms (f32) fused
  gemm128_fp8<2><<<grid, 256, 0, stream>>>(h1q, w2q, HID, HID, b2, h2q, norms);
  // triangular gram + classifier (fp8, single-buffer TLP, 528 blocks)
  gram_tri<<<528, 256, 0, stream>>>(h2q, HID, norms, Wc, out);
}

// Round 15
// 187.862 us; speedup vs baseline: 1.1095x; 1.0126x over previous
//
#include <hip/hip_runtime.h>
#include <hip/hip_bf16.h>

// FraudDetectionHybrid: h1=tanh(x@W1^T+b1); h2=tanh(h1@W2^T+b2);
// sq_ij=|h2_i|^2+|h2_j|^2-2*h2_i.h2_j; out=exp(-g*sq)@Wc^T+bc
// All-fp8 (e4m3, unit MX scales, data pre-scaled by 2^k), 16x16x128 MFMA,
// zero-conflict 16-row fragment shape (2-region LDS, 64B rows).
// R15 = R14 with ONE change: gram_tri __launch_bounds__(256,2) -> (256,4)
// (force 4 blocks/CU co-residency, the proven gemm128 occupancy lever;
//  also washes out the 528-block makespan-quantization tail).

#define NROWS 4096
#define HID   4096
#define INDIM 512
#define GAMMA_F 5e-4f

typedef float f32x4  __attribute__((ext_vector_type(4)));
typedef int   i32x4  __attribute__((ext_vector_type(4)));
typedef int   i32x8  __attribute__((ext_vector_type(8)));

#define SCALE1 0x7F7F7F7F   // e8m0 = 127 -> 2^0 in all bytes; opsel-independent

#define MFMA16(d, a, b) \
    d = __builtin_amdgcn_mfma_scale_f32_16x16x128_f8f6f4( \
        a, b, d, 0, 0, 0, SCALE1, 0, SCALE1)

// f32 -> OCP e4m3fn, RNE, saturate to 448, subnormals handled
__device__ __forceinline__ unsigned char f2e4m3(float x) {
  unsigned int u = __float_as_uint(x);
  unsigned char s = (unsigned char)((u >> 24) & 0x80u);
  float a = fabsf(x);
  if (a >= 448.f) return s | 0x7E;
  if (a < 0.015625f) {                      // below 2^-6: subnormal (2^-9 ulp)
    int q = (int)rintf(a * 512.f);
    return s | (unsigned char)q;
  }
  unsigned int ua = u & 0x7fffffffu;
  ua += 0x7FFFFu + ((ua >> 20) & 1u);       // RNE at mantissa bit 20
  int e = (int)(ua >> 23) - 127;
  unsigned int m = (ua >> 20) & 7u;
  return s | (unsigned char)(((e + 7) << 3) | m);
}

// fused: out/norms init + cast x*16, W1*32, W2*128 to fp8 (8-float chunks)
__global__ void prep(const float* __restrict__ x, const float* __restrict__ W1,
                     const float* __restrict__ W2, const float* __restrict__ bc,
                     unsigned char* __restrict__ xq, unsigned char* __restrict__ w1q,
                     unsigned char* __restrict__ w2q,
                     float* __restrict__ out, float* __restrict__ norms) {
  const int gi = blockIdx.x * blockDim.x + threadIdx.x;
  if (gi < NROWS) { out[gi] = bc[0]; norms[gi] = 0.f; }
  const int NX  = NROWS * INDIM / 8;
  const int NW2 = HID * HID / 8;
  const int total = 2 * NX + NW2;
  const int stride = gridDim.x * blockDim.x;
  for (int i = gi; i < total; i += stride) {
    const float* src; unsigned char* dst; float sc; int j;
    if (i < NX)          { src = x;  dst = xq;  sc = 16.f;  j = i; }
    else if (i < 2 * NX) { src = W1; dst = w1q; sc = 32.f;  j = i - NX; }
    else                 { src = W2; dst = w2q; sc = 128.f; j = i - 2 * NX; }
    float4 v0 = ((const float4*)src)[j * 2];
    float4 v1 = ((const float4*)src)[j * 2 + 1];
    unsigned int r0 = (unsigned int)f2e4m3(v0.x * sc)
                    | ((unsigned int)f2e4m3(v0.y * sc) << 8)
                    | ((unsigned int)f2e4m3(v0.z * sc) << 16)
                    | ((unsigned int)f2e4m3(v0.w * sc) << 24);
    unsigned int r1 = (unsigned int)f2e4m3(v1.x * sc)
                    | ((unsigned int)f2e4m3(v1.y * sc) << 8)
                    | ((unsigned int)f2e4m3(v1.z * sc) << 16)
                    | ((unsigned int)f2e4m3(v1.w * sc) << 24);
    uint2 o; o.x = r0; o.y = r1;
    ((uint2*)dst)[j] = o;
  }
}

__device__ __forceinline__ void gload16(const void* g, void* l) {
  __builtin_amdgcn_global_load_lds(
      (const __attribute__((address_space(1))) void*)g,
      (__attribute__((address_space(3))) void*)l, 16, 0, 0);
}

// one i32x8 operand = two b128 from the two LDS regions
#define LDFRAG(dst, base0, off, RSTRIDE) do {                       \
    i32x4 lo_ = *(const i32x4*)((base0) + (off));                   \
    i32x4 hi_ = *(const i32x4*)((base0) + (RSTRIDE) + (off));       \
    dst = __builtin_shufflevector(lo_, hi_, 0, 1, 2, 3, 4, 5, 6, 7); } while (0)

// ---------------------------------------------------------------------------
// fp8 NT GEMM (R11/R13/R14-verified, ~92us): BM=BN=128, BK=128 B, 4 waves
// (2x2), wave tile 64x64 = 4mi x 4nj of 16x16, K=128/MFMA. 32 KiB
// single-buffer -> 4 blocks/CU: cross-block TLP hides the drains.
// EPI 0: Hout = e4m3(8*tanh(acc/512 + bias));
// EPI 2: Hout = e4m3(8*tanh(acc/1024 + bias)) + row-norm atomics (f32 v).
// ---------------------------------------------------------------------------
template <int EPI>
__global__ __launch_bounds__(256, 4)
void gemm128_fp8(const unsigned char* __restrict__ A, const unsigned char* __restrict__ B,
                 int K, int N,
                 const float* __restrict__ bias, unsigned char* __restrict__ Hout,
                 float* __restrict__ norms_out) {
  __shared__ __align__(16) unsigned char As[2][128 * 64];
  __shared__ __align__(16) unsigned char Bs[2][128 * 64];

  const int tid  = threadIdx.x;
  const int lane = tid & 63;
  const int wave = tid >> 6;
  const int wr = wave >> 1, wc = wave & 1;   // 2x2 wave grid, 64x64 out each
  const int fr = lane & 15, fq = lane >> 4;

  const int nwg = gridDim.x;                  // 1024, %8==0
  const int cpx = nwg >> 3;
  const int bid = blockIdx.x;
  const int swzb = (bid & 7) * cpx + (bid >> 3);
  const int nbx = N >> 7;
  const int brow = (swzb / nbx) << 7;
  const int bcol = (swzb % nbx) << 7;

  const unsigned char* ap[4]; const unsigned char* bp[4]; int ldq[4];
#pragma unroll
  for (int q = 0; q < 4; ++q) {
    int idx = q * 256 + tid;
    int h   = idx >> 9;
    int row = (idx >> 2) & 127;
    int c   = idx & 3;
    int gcol = ((((c ^ ((row >> 1) & 3)) << 1) | h) << 4);
    ap[q] = A + (size_t)(brow + row) * K + gcol;
    bp[q] = B + (size_t)(bcol + row) * K + gcol;
    ldq[q] = (q * 256 + wave * 64) * 16;
  }

  int aoff[4], boff[4];
#pragma unroll
  for (int mi = 0; mi < 4; ++mi) {
    int row = wr * 64 + mi * 16 + fr;
    aoff[mi] = row * 64 + ((fq ^ ((row >> 1) & 3)) << 4);
  }
#pragma unroll
  for (int nj = 0; nj < 4; ++nj) {
    int row = wc * 64 + nj * 16 + fr;
    boff[nj] = row * 64 + ((fq ^ ((row >> 1) & 3)) << 4);
  }

  f32x4 acc[4][4] = {};

  for (int t = 0; t < (K >> 7); ++t) {
    __syncthreads();                 // WAR: previous tile's reads done
    {
      int kk = t * 128;
      gload16(ap[0] + kk, &As[0][0] + ldq[0]);
      gload16(ap[1] + kk, &As[0][0] + ldq[1]);
      gload16(ap[2] + kk, &As[0][0] + ldq[2]);
      gload16(ap[3] + kk, &As[0][0] + ldq[3]);
      gload16(bp[0] + kk, &Bs[0][0] + ldq[0]);
      gload16(bp[1] + kk, &Bs[0][0] + ldq[1]);
      gload16(bp[2] + kk, &Bs[0][0] + ldq[2]);
      gload16(bp[3] + kk, &Bs[0][0] + ldq[3]);
    }
    __syncthreads();                 // implicit vmcnt(0): staging landed

    i32x8 af[4], bf[4];
#pragma unroll
    for (int mi = 0; mi < 4; ++mi) LDFRAG(af[mi], &As[0][0], aoff[mi], 8192);
#pragma unroll
    for (int nj = 0; nj < 4; ++nj) LDFRAG(bf[nj], &Bs[0][0], boff[nj], 8192);
#pragma unroll
    for (int mi = 0; mi < 4; ++mi)
#pragma unroll
      for (int nj = 0; nj < 4; ++nj) MFMA16(acc[mi][nj], af[mi], bf[nj]);
  }

  // C/D layout (16x16): col = lane&15, row = (lane>>4)*4 + reg
  const float rescale = (EPI == 0) ? (1.f / 512.f) : (1.f / 1024.f);
  float bv[4];
#pragma unroll
  for (int nj = 0; nj < 4; ++nj) bv[nj] = bias[bcol + wc * 64 + nj * 16 + fr];
#pragma unroll
  for (int mi = 0; mi < 4; ++mi) {
    int row0 = brow + wr * 64 + mi * 16 + fq * 4;
#pragma unroll
    for (int rr = 0; rr < 4; ++rr) {
      float ns = 0.f;
#pragma unroll
      for (int nj = 0; nj < 4; ++nj) {
        int col = bcol + wc * 64 + nj * 16 + fr;
        float v = tanhf(acc[mi][nj][rr] * rescale + bv[nj]);
        Hout[(size_t)(row0 + rr) * N + col] = f2e4m3(8.f * v);
        if (EPI == 2) ns += v * v;
      }
      if (EPI == 2) {
        ns += __shfl_xor(ns, 1);
        ns += __shfl_xor(ns, 2);
        ns += __shfl_xor(ns, 4);
        ns += __shfl_xor(ns, 8);
        if (fr == 0) atomicAdd(&norms_out[row0 + rr], ns);
      }
    }
  }
}

// ---------------------------------------------------------------------------
// Triangular gram, fp8 (R7/R10/R14 structure, 72.6us at launch_bounds(256,2)):
// 128x128 tiles over the lower triangle (528 blocks), 4 waves (2x2),
// single-buffer 2-barrier loop, 32 KiB LDS. R15: launch_bounds(256,4) forces
// VGPR<=128 -> 4 blocks/CU co-residency (the verified gemm128 lever).
// sq = n_r + n_c - acc/32.
// ---------------------------------------------------------------------------
__global__ __launch_bounds__(256, 4)
void gram_tri(const unsigned char* __restrict__ H, int K,
              const float* __restrict__ norms, const float* __restrict__ Wc,
              float* __restrict__ out) {
  __shared__ __align__(16) unsigned char As[2][128 * 64];
  __shared__ __align__(16) unsigned char Bs[2][128 * 64];

  const int tid  = threadIdx.x;
  const int lane = tid & 63;
  const int wave = tid >> 6;
  const int wr = wave >> 1, wc = wave & 1;
  const int fr = lane & 15, fq = lane >> 4;

  const int bid = blockIdx.x;
  const int swzb = (bid & 7) * 66 + (bid >> 3);
  int I = (int)((sqrtf(8.0f * (float)swzb + 1.0f) - 1.0f) * 0.5f);
  while ((I + 1) * (I + 2) / 2 <= swzb) ++I;
  while (I * (I + 1) / 2 > swzb) --I;
  const int J = swzb - I * (I + 1) / 2;
  const int brow = I << 7, bcol = J << 7;
  const bool diag = (I == J);

  const unsigned char* ap[4]; const unsigned char* bp[4]; int ldq[4];
#pragma unroll
  for (int q = 0; q < 4; ++q) {
    int idx = q * 256 + tid;
    int h   = idx >> 9;
    int row = (idx >> 2) & 127;
    int c   = idx & 3;
    int gcol = ((((c ^ ((row >> 1) & 3)) << 1) | h) << 4);
    ap[q] = H + (size_t)(brow + row) * K + gcol;
    bp[q] = H + (size_t)(bcol + row) * K + gcol;
    ldq[q] = (q * 256 + wave * 64) * 16;
  }

  int aoff[4], boff[4];
#pragma unroll
  for (int mi = 0; mi < 4; ++mi) {
    int row = wr * 64 + mi * 16 + fr;
    aoff[mi] = row * 64 + ((fq ^ ((row >> 1) & 3)) << 4);
  }
#pragma unroll
  for (int nj = 0; nj < 4; ++nj) {
    int row = wc * 64 + nj * 16 + fr;
    boff[nj] = row * 64 + ((fq ^ ((row >> 1) & 3)) << 4);
  }

  f32x4 acc[4][4] = {};

  for (int t = 0; t < (K >> 7); ++t) {
    __syncthreads();
    {
      int kk = t * 128;
      gload16(ap[0] + kk, &As[0][0] + ldq[0]);
      gload16(ap[1] + kk, &As[0][0] + ldq[1]);
      gload16(ap[2] + kk, &As[0][0] + ldq[2]);
      gload16(ap[3] + kk, &As[0][0] + ldq[3]);
      gload16(bp[0] + kk, &Bs[0][0] + ldq[0]);
      gload16(bp[1] + kk, &Bs[0][0] + ldq[1]);
      gload16(bp[2] + kk, &Bs[0][0] + ldq[2]);
      gload16(bp[3] + kk, &Bs[0][0] + ldq[3]);
    }
    __syncthreads();   // implicit vmcnt(0) drain: staging landed

    i32x8 af[4], bf[4];
#pragma unroll
    for (int mi = 0; mi < 4; ++mi) LDFRAG(af[mi], &As[0][0], aoff[mi], 8192);
#pragma unroll
    for (int nj = 0; nj < 4; ++nj) LDFRAG(bf[nj], &Bs[0][0], boff[nj], 8192);
#pragma unroll
    for (int mi = 0; mi < 4; ++mi)
#pragma unroll
      for (int nj = 0; nj < 4; ++nj)
        acc[mi][nj] = __builtin_amdgcn_mfma_scale_f32_16x16x128_f8f6f4(
            af[mi], bf[nj], acc[mi][nj], 0, 0, 0, SCALE1, 0, SCALE1);
  }

  // epilogue: sq = n_r + n_c - acc/32 ; dual-direction reduction
  float ncol[4], wcv[4];
#pragma unroll
  for (int nj = 0; nj < 4; ++nj) {
    int col = bcol + wc * 64 + nj * 16 + fr;
    ncol[nj] = norms[col];
    wcv[nj]  = Wc[col];
  }
  float colpart[4] = {0.f, 0.f, 0.f, 0.f};
#pragma unroll
  for (int mi = 0; mi < 4; ++mi) {
    int row0 = brow + wr * 64 + mi * 16 + fq * 4;
    float4 nr4  = *(const float4*)&norms[row0];
    float4 wcr4 = *(const float4*)&Wc[row0];
#pragma unroll
    for (int rr = 0; rr < 4; ++rr) {
      float nrow = (rr == 0) ? nr4.x : (rr == 1) ? nr4.y : (rr == 2) ? nr4.z : nr4.w;
      float wrow = (rr == 0) ? wcr4.x : (rr == 1) ? wcr4.y : (rr == 2) ? wcr4.z : wcr4.w;
      float rowpart = 0.f;
#pragma unroll
      for (int nj = 0; nj < 4; ++nj) {
        float sq = nrow + ncol[nj] - acc[mi][nj][rr] * 0.03125f;
        float e = __expf(-GAMMA_F * sq);
        rowpart += e * wcv[nj];
        colpart[nj] += e * wrow;
      }
      rowpart += __shfl_xor(rowpart, 1);
      rowpart += __shfl_xor(rowpart, 2);
      rowpart += __shfl_xor(rowpart, 4);
      rowpart += __shfl_xor(rowpart, 8);
      if (fr == 0) atomicAdd(&out[row0 + rr], rowpart);
    }
  }
  if (!diag) {
#pragma unroll
    for (int nj = 0; nj < 4; ++nj) {
      colpart[nj] += __shfl_xor(colpart[nj], 16);
      colpart[nj] += __shfl_xor(colpart[nj], 32);
      if (fq == 0) atomicAdd(&out[bcol + wc * 64 + nj * 16 + fr], colpart[nj]);
    }
  }
}

extern "C" void kernel_launch(void* const* d_in, const int* in_sizes, int n_in,
                              void* d_out, int out_size, void* d_ws, size_t ws_size,
                              hipStream_t stream) {
  const float* x  = (const float*)d_in[0];  // [4096,512]
  const float* W1 = (const float*)d_in[1];  // [4096,512]
  const float* b1 = (const float*)d_in[2];  // [4096]
  const float* W2 = (const float*)d_in[3];  // [4096,4096]
  const float* b2 = (const float*)d_in[4];  // [4096]
  const float* Wc = (const float*)d_in[5];  // [1,4096]
  const float* bc = (const float*)d_in[6];  // [1]
  float* out = (float*)d_out;               // [4096,1]

  char* ws = (char*)d_ws;
  unsigned char* xq  = (unsigned char*)ws; ws += (size_t)NROWS * INDIM;   // x*16   fp8
  unsigned char* w1q = (unsigned char*)ws; ws += (size_t)HID * INDIM;     // W1*32  fp8
  unsigned char* w2q = (unsigned char*)ws; ws += (size_t)HID * HID;       // W2*128 fp8
  unsigned char* h1q = (unsigned char*)ws; ws += (size_t)NROWS * HID;     // h1*8   fp8
  unsigned char* h2q = (unsigned char*)ws; ws += (size_t)NROWS * HID;     // h2*8   fp8
  float* norms = (float*)ws;                ws += (size_t)NROWS * 4;

  // fused init + casts
  prep<<<2048, 256, 0, stream>>>(x, W1, W2, bc, xq, w1q, w2q, out, norms);

  const int grid = (NROWS / 128) * (HID / 128);  // 1024

  // h1 = tanh((x16 @ W1_32^T)/512 + b1) -> fp8(8*h1)
  gemm128_fp8<0><<<grid, 256, 0, stream>>>(xq, w1q, INDIM, HID, b1, h1q, nullptr);
  // h2 = tanh((h1_8 @ W2_128^T)/1024 + b2) -> fp8(8*h2), norms (f32) fused
  gemm128_fp8<2><<<grid, 256, 0, stream>>>(h1q, w2q, HID, HID, b2, h2q, norms);
  // triangular gram + classifier (fp8, single-buffer, 4 blocks/CU)
  gram_tri<<<528, 256, 0, stream>>>(h2q, HID, norms, Wc, out);
}